// Round 1
// baseline (681.277 us; speedup 1.0000x reference)
//
#include <hip/hip_runtime.h>
#include <math.h>

#define B 8
#define N 8192
#define S 2048
#define C 256
#define CIN 512
#define CNT (B * N)  // 65536

// ---------------- 3-NN: top-3 smallest distances per query point ----------------
__global__ __launch_bounds__(256) void nn3_kernel(const float* __restrict__ xyz1,
                                                  const float* __restrict__ xyz2,
                                                  int* __restrict__ idxbuf,
                                                  float* __restrict__ wbuf) {
  __shared__ float sx[S], sy[S], sz[S], s2[S];
  int b = blockIdx.x >> 5;           // N/256 = 32 blocks per batch
  int n0 = (blockIdx.x & 31) * 256;
  const float* p2 = xyz2 + (size_t)b * 3 * S;
  for (int i = threadIdx.x; i < S; i += 256) {
    float px = p2[i], py = p2[S + i], pz = p2[2 * S + i];
    sx[i] = px; sy[i] = py; sz[i] = pz;
    s2[i] = px * px + py * py + pz * pz;
  }
  __syncthreads();
  int n = n0 + threadIdx.x;
  const float* p1 = xyz1 + (size_t)b * 3 * N;
  float qx = p1[n], qy = p1[N + n], qz = p1[2 * N + n];
  float q2 = qx * qx + qy * qy + qz * qz;
  float d0 = INFINITY, d1 = INFINITY, d2 = INFINITY;
  int i0 = 0, i1 = 0, i2 = 0;
  for (int s = 0; s < S; ++s) {
    float d = q2 + s2[s] - 2.0f * (qx * sx[s] + qy * sy[s] + qz * sz[s]);
    if (d < d2) {
      if (d < d1) {
        d2 = d1; i2 = i1;
        if (d < d0) { d1 = d0; i1 = i0; d0 = d; i0 = s; }
        else { d1 = d; i1 = s; }
      } else { d2 = d; i2 = s; }
    }
  }
  float r0 = 1.0f / (d0 + 1e-8f);
  float r1 = 1.0f / (d1 + 1e-8f);
  float r2 = 1.0f / (d2 + 1e-8f);
  float rs = 1.0f / (r0 + r1 + r2);
  size_t o = ((size_t)b * N + n) * 3;
  idxbuf[o] = i0; idxbuf[o + 1] = i1; idxbuf[o + 2] = i2;
  wbuf[o] = r0 * rs; wbuf[o + 1] = r1 * rs; wbuf[o + 2] = r2 * rs;
}

// ---------------- gather: interp[b,c,n] = sum_j w_j * points2[b,c,idx_j] ----------------
__global__ __launch_bounds__(256) void gather_kernel(const float* __restrict__ p2,
                                                     const int* __restrict__ idxbuf,
                                                     const float* __restrict__ wbuf,
                                                     float* __restrict__ interp) {
  __shared__ int si[192];
  __shared__ float sw[192];
  int b = blockIdx.x >> 7;           // N/64 = 128 blocks per batch
  int n0 = (blockIdx.x & 127) * 64;
  size_t base = ((size_t)b * N + n0) * 3;
  if (threadIdx.x < 192) {
    si[threadIdx.x] = idxbuf[base + threadIdx.x];
    sw[threadIdx.x] = wbuf[base + threadIdx.x];
  }
  __syncthreads();
  int tn = threadIdx.x & 63;
  int cq = threadIdx.x >> 6;
  int j0 = si[tn * 3], j1 = si[tn * 3 + 1], j2 = si[tn * 3 + 2];
  float w0 = sw[tn * 3], w1 = sw[tn * 3 + 1], w2 = sw[tn * 3 + 2];
  const float* pb = p2 + (size_t)b * C * S;
  for (int c = cq; c < C; c += 4) {
    const float* row = pb + (size_t)c * S;
    float v = w0 * row[j0] + w1 * row[j1] + w2 * row[j2];
    interp[((size_t)b * C + c) * N + n0 + tn] = v;
  }
}

// ---------------- f32 vector GEMM: Y[b,o,n] = bias[o] + sum_c W[o,c] X[b,c,n] ----------------
// X split over two pointers (X0: c<256, X1: c>=256) to handle the concat without materializing it.
__global__ __launch_bounds__(256) void gemm_kernel(const float* __restrict__ X0,
                                                   const float* __restrict__ X1,
                                                   const float* __restrict__ W,
                                                   const float* __restrict__ bias,
                                                   float* __restrict__ Y,
                                                   int Cin) {
  __shared__ float As[16][128];  // [kk][oo]
  __shared__ float Bs[16][128];  // [kk][nn]
  int n0 = blockIdx.x * 128;
  int o0 = blockIdx.y * 128;
  int b = blockIdx.z;
  int tid = threadIdx.x;
  int tr = tid >> 4, tc = tid & 15;
  float acc[8][8];
#pragma unroll
  for (int i = 0; i < 8; ++i)
#pragma unroll
    for (int j = 0; j < 8; ++j) acc[i][j] = 0.f;

  for (int k0 = 0; k0 < Cin; k0 += 16) {
    const float* Xs;
    int kb;
    if (X1 != nullptr && k0 >= 256) { Xs = X1; kb = k0 - 256; }
    else { Xs = X0; kb = k0; }
    const float* Xp = Xs + ((size_t)b * 256 + kb) * N + n0;
    // B tile: 16 x 128 (float4, coalesced)
#pragma unroll
    for (int i = 0; i < 2; ++i) {
      int fid = tid + i * 256;  // 0..511
      int kk = fid >> 5, nn4 = fid & 31;
      float4 v = *(const float4*)(Xp + (size_t)kk * N + nn4 * 4);
      *(float4*)&Bs[kk][nn4 * 4] = v;
    }
    // A tile: 128 x 16, transpose into [kk][oo]
#pragma unroll
    for (int i = 0; i < 2; ++i) {
      int fid = tid + i * 256;  // 0..511
      int oo = fid >> 2, kq = fid & 3;
      float4 v = *(const float4*)(W + (size_t)(o0 + oo) * Cin + k0 + kq * 4);
      As[kq * 4 + 0][oo] = v.x;
      As[kq * 4 + 1][oo] = v.y;
      As[kq * 4 + 2][oo] = v.z;
      As[kq * 4 + 3][oo] = v.w;
    }
    __syncthreads();
#pragma unroll
    for (int kk = 0; kk < 16; ++kk) {
      float4 a0 = *(const float4*)&As[kk][tr * 4];
      float4 a1 = *(const float4*)&As[kk][64 + tr * 4];
      float4 bq0 = *(const float4*)&Bs[kk][tc * 4];
      float4 bq1 = *(const float4*)&Bs[kk][64 + tc * 4];
      float av[8] = {a0.x, a0.y, a0.z, a0.w, a1.x, a1.y, a1.z, a1.w};
      float bv[8] = {bq0.x, bq0.y, bq0.z, bq0.w, bq1.x, bq1.y, bq1.z, bq1.w};
#pragma unroll
      for (int i = 0; i < 8; ++i)
#pragma unroll
        for (int j = 0; j < 8; ++j) acc[i][j] = fmaf(av[i], bv[j], acc[i][j]);
    }
    __syncthreads();
  }
#pragma unroll
  for (int i = 0; i < 8; ++i) {
    int o = o0 + ((i < 4) ? (tr * 4 + i) : (64 + tr * 4 + (i - 4)));
    float bs = bias[o];
    float* yrow = Y + ((size_t)b * C + o) * N + n0;
    float4 v0 = make_float4(acc[i][0] + bs, acc[i][1] + bs, acc[i][2] + bs, acc[i][3] + bs);
    float4 v1 = make_float4(acc[i][4] + bs, acc[i][5] + bs, acc[i][6] + bs, acc[i][7] + bs);
    *(float4*)(yrow + tc * 4) = v0;
    *(float4*)(yrow + 64 + tc * 4) = v1;
  }
}

// ---------------- per-channel sum/sumsq over (B, N) ----------------
__global__ __launch_bounds__(256) void stats_kernel(const float* __restrict__ Y,
                                                    float* __restrict__ sum,
                                                    float* __restrict__ sumsq) {
  int c = blockIdx.x, b = blockIdx.y;
  const float4* p = (const float4*)(Y + ((size_t)b * C + c) * N);
  float s = 0.f, q = 0.f;
  for (int i = threadIdx.x; i < N / 4; i += 256) {
    float4 v = p[i];
    s += v.x + v.y + v.z + v.w;
    q += v.x * v.x + v.y * v.y + v.z * v.z + v.w * v.w;
  }
  for (int off = 32; off > 0; off >>= 1) {
    s += __shfl_down(s, off);
    q += __shfl_down(q, off);
  }
  __shared__ float ls[4], lq[4];
  int wid = threadIdx.x >> 6, lane = threadIdx.x & 63;
  if (lane == 0) { ls[wid] = s; lq[wid] = q; }
  __syncthreads();
  if (threadIdx.x == 0) {
    atomicAdd(&sum[c], ls[0] + ls[1] + ls[2] + ls[3]);
    atomicAdd(&sumsq[c], lq[0] + lq[1] + lq[2] + lq[3]);
  }
}

__global__ void bnparam_kernel(const float* __restrict__ sum, const float* __restrict__ sumsq,
                               const float* __restrict__ gamma, const float* __restrict__ beta,
                               float* __restrict__ scale, float* __restrict__ shift) {
  int c = threadIdx.x;
  float m = sum[c] * (1.0f / CNT);
  float v = sumsq[c] * (1.0f / CNT) - m * m;
  float sc = gamma[c] * rsqrtf(v + 1e-5f);
  scale[c] = sc;
  shift[c] = beta[c] - m * sc;
}

__global__ __launch_bounds__(256) void bnrelu_kernel(const float* __restrict__ Y,
                                                     const float* __restrict__ scale,
                                                     const float* __restrict__ shift,
                                                     float* __restrict__ Hout) {
  size_t total = (size_t)B * C * N / 4;
  for (size_t i = (size_t)blockIdx.x * 256 + threadIdx.x; i < total;
       i += (size_t)gridDim.x * 256) {
    int c = (int)((i >> 11) & 255);  // N/4 = 2048 float4 per (b,c) row
    float sc = scale[c], sh = shift[c];
    float4 v = ((const float4*)Y)[i];
    v.x = fmaxf(fmaf(v.x, sc, sh), 0.f);
    v.y = fmaxf(fmaf(v.y, sc, sh), 0.f);
    v.z = fmaxf(fmaf(v.z, sc, sh), 0.f);
    v.w = fmaxf(fmaf(v.w, sc, sh), 0.f);
    ((float4*)Hout)[i] = v;
  }
}

extern "C" void kernel_launch(void* const* d_in, const int* in_sizes, int n_in,
                              void* d_out, int out_size, void* d_ws, size_t ws_size,
                              hipStream_t stream) {
  const float* xyz1 = (const float*)d_in[0];
  const float* xyz2 = (const float*)d_in[1];
  const float* points1 = (const float*)d_in[2];
  const float* points2 = (const float*)d_in[3];
  const float* w0 = (const float*)d_in[4];
  const float* b0 = (const float*)d_in[5];
  const float* g0 = (const float*)d_in[6];
  const float* be0 = (const float*)d_in[7];
  const float* w1 = (const float*)d_in[8];
  const float* b1 = (const float*)d_in[9];
  const float* g1 = (const float*)d_in[10];
  const float* be1 = (const float*)d_in[11];
  float* out = (float*)d_out;

  char* ws = (char*)d_ws;
  int* idxbuf = (int*)ws;            ws += (size_t)CNT * 3 * 4;
  float* wbuf = (float*)ws;          ws += (size_t)CNT * 3 * 4;
  float* stats = (float*)ws;         ws += (size_t)8 * 256 * 4;
  float* sum0 = stats,        *sumsq0 = stats + 256;
  float* sum1 = stats + 512,  *sumsq1 = stats + 768;
  float* scale0 = stats + 1024, *shift0 = stats + 1280;
  float* scale1 = stats + 1536, *shift1 = stats + 1792;
  float* interp = (float*)ws;        ws += (size_t)B * C * N * 4;  // also reused as h
  float* ybuf = (float*)ws;

  hipMemsetAsync(stats, 0, 4 * 256 * 4, stream);
  nn3_kernel<<<dim3(B * N / 256), 256, 0, stream>>>(xyz1, xyz2, idxbuf, wbuf);
  gather_kernel<<<dim3(B * N / 64), 256, 0, stream>>>(points2, idxbuf, wbuf, interp);
  gemm_kernel<<<dim3(N / 128, C / 128, B), 256, 0, stream>>>(points1, interp, w0, b0, ybuf, CIN);
  stats_kernel<<<dim3(C, B), 256, 0, stream>>>(ybuf, sum0, sumsq0);
  bnparam_kernel<<<1, 256, 0, stream>>>(sum0, sumsq0, g0, be0, scale0, shift0);
  bnrelu_kernel<<<4096, 256, 0, stream>>>(ybuf, scale0, shift0, interp);
  gemm_kernel<<<dim3(N / 128, C / 128, B), 256, 0, stream>>>(interp, nullptr, w1, b1, out, C);
  stats_kernel<<<dim3(C, B), 256, 0, stream>>>(out, sum1, sumsq1);
  bnparam_kernel<<<1, 256, 0, stream>>>(sum1, sumsq1, g1, be1, scale1, shift1);
  bnrelu_kernel<<<4096, 256, 0, stream>>>(out, scale1, shift1, out);
}

// Round 2
// 252.045 us; speedup vs baseline: 2.7030x; 2.7030x over previous
//
#include <hip/hip_runtime.h>
#include <math.h>

#define B 8
#define N 8192
#define S 2048
#define C 256
#define CIN 512
#define CNT (B * N)  // 65536

typedef __attribute__((ext_vector_type(8))) short bf16x8;
typedef __attribute__((ext_vector_type(4))) float floatx4;
typedef __attribute__((ext_vector_type(8))) unsigned short ushort8v;
typedef __attribute__((ext_vector_type(4))) unsigned short ushort4v;

__device__ inline unsigned short f2bf(float f) {
  unsigned u = __builtin_bit_cast(unsigned, f);
  u += 0x7FFF + ((u >> 16) & 1);  // RNE
  return (unsigned short)(u >> 16);
}
__device__ inline float bf2f(unsigned short h) {
  unsigned u = ((unsigned)h) << 16;
  return __builtin_bit_cast(float, u);
}

__device__ inline void load_lds16(const void* g, void* l) {
  __builtin_amdgcn_global_load_lds(
      (const __attribute__((address_space(1))) unsigned int*)g,
      (__attribute__((address_space(3))) unsigned int*)l, 16, 0, 0);
}

// ---------------- 3-NN v2: 4 threads per query, shfl merge ----------------
__device__ inline void ins3(float d, int i, float& d0, int& i0, float& d1, int& i1,
                            float& d2, int& i2) {
  bool lt2 = (d < d2) || (d == d2 && i < i2);
  if (lt2) {
    bool lt1 = (d < d1) || (d == d1 && i < i1);
    bool lt0 = (d < d0) || (d == d0 && i < i0);
    if (lt0) { d2 = d1; i2 = i1; d1 = d0; i1 = i0; d0 = d; i0 = i; }
    else if (lt1) { d2 = d1; i2 = i1; d1 = d; i1 = i; }
    else { d2 = d; i2 = i; }
  }
}

__global__ __launch_bounds__(256) void nn3_kernel(const float* __restrict__ xyz1,
                                                  const float* __restrict__ xyz2,
                                                  int* __restrict__ idxbuf,
                                                  float* __restrict__ wbuf) {
  __shared__ float4 sp[S];  // {x,y,z,|p|^2}  32KB
  int b = blockIdx.x >> 7;           // grid = B * (N/64) = 1024
  int n0 = (blockIdx.x & 127) * 64;
  const float* p2 = xyz2 + (size_t)b * 3 * S;
  for (int i = threadIdx.x; i < S; i += 256) {
    float px = p2[i], py = p2[S + i], pz = p2[2 * S + i];
    sp[i] = make_float4(px, py, pz, px * px + py * py + pz * pz);
  }
  __syncthreads();
  int tid = threadIdx.x;
  int nl = tid >> 2, sub = tid & 3;
  int n = n0 + nl;
  const float* p1 = xyz1 + (size_t)b * 3 * N;
  float qx = p1[n], qy = p1[N + n], qz = p1[2 * N + n];
  float q2 = qx * qx + qy * qy + qz * qz;
  float d0 = INFINITY, d1 = INFINITY, d2 = INFINITY;
  int i0 = 0, i1 = 0, i2 = 0;
  int base = sub * 512;
  for (int t = 0; t < 512; ++t) {
    int s = base + ((t + sub) & 511);  // stagger: 4 sub-groups hit distinct bank quads
    float4 p = sp[s];
    float dot = qx * p.x + qy * p.y + qz * p.z;
    float d = q2 + p.w - 2.0f * dot;
    if (d < d2) {
      if (d < d1) {
        d2 = d1; i2 = i1;
        if (d < d0) { d1 = d0; i1 = i0; d0 = d; i0 = s; }
        else { d1 = d; i1 = s; }
      } else { d2 = d; i2 = s; }
    }
  }
  // merge across the 4 sub-lanes (adjacent lanes in wave)
#pragma unroll
  for (int m = 1; m <= 2; m <<= 1) {
    float e0 = __shfl_xor(d0, m), e1 = __shfl_xor(d1, m), e2 = __shfl_xor(d2, m);
    int j0 = __shfl_xor(i0, m), j1 = __shfl_xor(i1, m), j2 = __shfl_xor(i2, m);
    ins3(e0, j0, d0, i0, d1, i1, d2, i2);
    ins3(e1, j1, d0, i0, d1, i1, d2, i2);
    ins3(e2, j2, d0, i0, d1, i1, d2, i2);
  }
  if (sub == 0) {
    float r0 = 1.0f / (d0 + 1e-8f);
    float r1 = 1.0f / (d1 + 1e-8f);
    float r2 = 1.0f / (d2 + 1e-8f);
    float rs = 1.0f / (r0 + r1 + r2);
    size_t o = ((size_t)b * N + n) * 3;
    idxbuf[o] = i0; idxbuf[o + 1] = i1; idxbuf[o + 2] = i2;
    wbuf[o] = r0 * rs; wbuf[o + 1] = r1 * rs; wbuf[o + 2] = r2 * rs;
  }
}

// ---------------- weights f32 -> bf16 ----------------
__global__ __launch_bounds__(256) void convw_kernel(const float* __restrict__ w0,
                                                    const float* __restrict__ w1,
                                                    unsigned short* __restrict__ w0b,
                                                    unsigned short* __restrict__ w1b) {
  int i = blockIdx.x * 256 + threadIdx.x;
  if (i < C * CIN) w0b[i] = f2bf(w0[i]);
  else {
    int j = i - C * CIN;
    if (j < C * C) w1b[j] = f2bf(w1[j]);
  }
}

// ---------------- transpose+convert: src[b][256][cols] f32 -> dst[b][cols][drow] bf16 ----------------
__global__ __launch_bounds__(256) void tconv_kernel(const float* __restrict__ src,
                                                    unsigned short* __restrict__ dst,
                                                    int cols, int drow, int coff) {
  __shared__ float t[64][65];
  int n0 = blockIdx.x * 64, c0 = blockIdx.y * 64, b = blockIdx.z;
  int tid = threadIdx.x, r = tid >> 2, q = tid & 3;
  const float* sp = src + ((size_t)b * 256 + c0 + r) * cols + n0 + q * 16;
#pragma unroll
  for (int i = 0; i < 4; ++i) {
    float4 v = *(const float4*)(sp + i * 4);
    t[r][q * 16 + i * 4 + 0] = v.x;
    t[r][q * 16 + i * 4 + 1] = v.y;
    t[r][q * 16 + i * 4 + 2] = v.z;
    t[r][q * 16 + i * 4 + 3] = v.w;
  }
  __syncthreads();
  unsigned short* dp = dst + ((size_t)b * cols + n0 + r) * drow + coff + c0 + q * 16;
  ushort8v o0, o1;
#pragma unroll
  for (int i = 0; i < 8; ++i) o0[i] = f2bf(t[q * 16 + i][r]);
#pragma unroll
  for (int i = 0; i < 8; ++i) o1[i] = f2bf(t[q * 16 + 8 + i][r]);
  *(ushort8v*)dp = o0;
  *(ushort8v*)(dp + 8) = o1;
}

// ---------------- gather: Xb[b][n][256+c] = sum_j w_j * p2t[b][idx_j][c] ----------------
__global__ __launch_bounds__(256) void gather_kernel(const unsigned short* __restrict__ p2t,
                                                     const int* __restrict__ idxbuf,
                                                     const float* __restrict__ wbuf,
                                                     unsigned short* __restrict__ Xb) {
  __shared__ int si[192];
  __shared__ float sw[192];
  int b = blockIdx.x >> 7;  // grid = B * (N/64)
  int n0 = (blockIdx.x & 127) * 64;
  size_t base = ((size_t)b * N + n0) * 3;
  if (threadIdx.x < 192) {
    si[threadIdx.x] = idxbuf[base + threadIdx.x];
    sw[threadIdx.x] = wbuf[base + threadIdx.x];
  }
  __syncthreads();
  int nl = threadIdx.x >> 2, cb = threadIdx.x & 3;
  int j0 = si[nl * 3], j1 = si[nl * 3 + 1], j2 = si[nl * 3 + 2];
  float w0 = sw[nl * 3], w1 = sw[nl * 3 + 1], w2 = sw[nl * 3 + 2];
  const unsigned short* pb = p2t + (size_t)b * S * 256;
  const unsigned short* r0p = pb + (size_t)j0 * 256;
  const unsigned short* r1p = pb + (size_t)j1 * 256;
  const unsigned short* r2p = pb + (size_t)j2 * 256;
  unsigned short* xp = Xb + ((size_t)b * N + n0 + nl) * 512 + 256;
#pragma unroll
  for (int ch = 0; ch < 8; ++ch) {
    int co = (cb + ch * 4) * 8;
    ushort8v v0 = *(const ushort8v*)(r0p + co);
    ushort8v v1 = *(const ushort8v*)(r1p + co);
    ushort8v v2 = *(const ushort8v*)(r2p + co);
    ushort8v o;
#pragma unroll
    for (int i = 0; i < 8; ++i)
      o[i] = f2bf(w0 * bf2f(v0[i]) + w1 * bf2f(v1[i]) + w2 * bf2f(v2[i]));
    *(ushort8v*)(xp + co) = o;
  }
}

// ---------------- bf16 MFMA GEMM: Y[b][n][o] = bias[o] + sum_k W[o][k] X[b][n][k] ----------------
__global__ __launch_bounds__(256) void gemm_kernel(const unsigned short* __restrict__ X,
                                                   const unsigned short* __restrict__ Wb,
                                                   const float* __restrict__ bias,
                                                   unsigned short* __restrict__ Y,
                                                   int Cin) {
  __shared__ unsigned short As[128 * 32];  // [o_row][k] 8KB
  __shared__ unsigned short Bs[128 * 32];  // [n_row][k] 8KB
  int n0 = blockIdx.x * 128, o0 = blockIdx.y * 128, b = blockIdx.z;
  int tid = threadIdx.x, lane = tid & 63, wid = tid >> 6;
  int wm = wid >> 1, wn = wid & 1;
  floatx4 acc[4][4];
#pragma unroll
  for (int m = 0; m < 4; ++m)
#pragma unroll
    for (int nt = 0; nt < 4; ++nt) acc[m][nt] = (floatx4)(0.0f);

  size_t rsA = (size_t)Cin * 2;  // row stride bytes
  const char* Abase = (const char*)Wb + (size_t)(o0 + wid * 32 + (lane >> 2)) * rsA + (lane & 3) * 16;
  const char* Bbase = (const char*)X + ((size_t)b * N + n0 + wid * 32 + (lane >> 2)) * rsA + (lane & 3) * 16;
  size_t rstep16 = 16 * rsA;
  int kq = (lane >> 4) * 8;

  for (int k0 = 0; k0 < Cin; k0 += 32) {
    load_lds16(Abase + (size_t)k0 * 2, &As[(wid * 32) * 32]);
    load_lds16(Abase + (size_t)k0 * 2 + rstep16, &As[(wid * 32 + 16) * 32]);
    load_lds16(Bbase + (size_t)k0 * 2, &Bs[(wid * 32) * 32]);
    load_lds16(Bbase + (size_t)k0 * 2 + rstep16, &Bs[(wid * 32 + 16) * 32]);
    __syncthreads();
    bf16x8 af[4], bfv[4];
#pragma unroll
    for (int m = 0; m < 4; ++m)
      af[m] = *(const bf16x8*)&As[(wm * 64 + m * 16 + (lane & 15)) * 32 + kq];
#pragma unroll
    for (int nt = 0; nt < 4; ++nt)
      bfv[nt] = *(const bf16x8*)&Bs[(wn * 64 + nt * 16 + (lane & 15)) * 32 + kq];
#pragma unroll
    for (int m = 0; m < 4; ++m)
#pragma unroll
      for (int nt = 0; nt < 4; ++nt)
        acc[m][nt] = __builtin_amdgcn_mfma_f32_16x16x32_bf16(af[m], bfv[nt], acc[m][nt], 0, 0, 0);
    __syncthreads();
  }

  int col = lane & 15, rowq = lane >> 4;
#pragma unroll
  for (int m = 0; m < 4; ++m) {
    int ob = o0 + wm * 64 + m * 16 + rowq * 4;
    float4 bs = *(const float4*)&bias[ob];
#pragma unroll
    for (int nt = 0; nt < 4; ++nt) {
      int n = n0 + wn * 64 + nt * 16 + col;
      ushort4v v;
      v[0] = f2bf(acc[m][nt][0] + bs.x);
      v[1] = f2bf(acc[m][nt][1] + bs.y);
      v[2] = f2bf(acc[m][nt][2] + bs.z);
      v[3] = f2bf(acc[m][nt][3] + bs.w);
      *(ushort4v*)&Y[((size_t)b * N + n) * 256 + ob] = v;
    }
  }
}

// ---------------- per-channel stats over bf16 Y[b][n][256] ----------------
__global__ __launch_bounds__(256) void stats_kernel(const unsigned short* __restrict__ Y,
                                                    float* __restrict__ sum,
                                                    float* __restrict__ sumsq) {
  __shared__ float ls[8][256], lq[8][256];
  int tid = threadIdx.x, och = tid & 31, nt = tid >> 5;
  size_t r0 = (size_t)blockIdx.x * 256 + nt;
  float s[8], q[8];
#pragma unroll
  for (int j = 0; j < 8; ++j) { s[j] = 0.f; q[j] = 0.f; }
  for (int i = 0; i < 32; ++i) {
    ushort8v v = *(const ushort8v*)&Y[(r0 + (size_t)i * 8) * 256 + och * 8];
#pragma unroll
    for (int j = 0; j < 8; ++j) {
      float f = bf2f(v[j]);
      s[j] += f; q[j] += f * f;
    }
  }
#pragma unroll
  for (int j = 0; j < 8; ++j) { ls[nt][och * 8 + j] = s[j]; lq[nt][och * 8 + j] = q[j]; }
  __syncthreads();
  float ss = 0.f, qq = 0.f;
#pragma unroll
  for (int i = 0; i < 8; ++i) { ss += ls[i][tid]; qq += lq[i][tid]; }
  atomicAdd(&sum[tid], ss);
  atomicAdd(&sumsq[tid], qq);
}

__global__ void bnparam_kernel(const float* __restrict__ sum, const float* __restrict__ sumsq,
                               const float* __restrict__ gamma, const float* __restrict__ beta,
                               float* __restrict__ scale, float* __restrict__ shift) {
  int c = threadIdx.x;
  float m = sum[c] * (1.0f / CNT);
  float v = sumsq[c] * (1.0f / CNT) - m * m;
  float sc = gamma[c] * rsqrtf(v + 1e-5f);
  scale[c] = sc;
  shift[c] = beta[c] - m * sc;
}

// ---------------- BN+ReLU elementwise on [b][n][256] bf16 -> bf16 ----------------
__global__ __launch_bounds__(256) void bnrelu_kernel(const unsigned short* __restrict__ Y,
                                                     const float* __restrict__ scale,
                                                     const float* __restrict__ shift,
                                                     unsigned short* __restrict__ H) {
  size_t total = (size_t)B * N * 256 / 8;
  for (size_t i = (size_t)blockIdx.x * 256 + threadIdx.x; i < total;
       i += (size_t)gridDim.x * 256) {
    int ob = ((int)i & 31) * 8;
    float4 s0 = *(const float4*)&scale[ob];
    float4 s1 = *(const float4*)&scale[ob + 4];
    float4 h0 = *(const float4*)&shift[ob];
    float4 h1 = *(const float4*)&shift[ob + 4];
    ushort8v v = *(const ushort8v*)&Y[i * 8];
    ushort8v o;
    o[0] = f2bf(fmaxf(fmaf(bf2f(v[0]), s0.x, h0.x), 0.f));
    o[1] = f2bf(fmaxf(fmaf(bf2f(v[1]), s0.y, h0.y), 0.f));
    o[2] = f2bf(fmaxf(fmaf(bf2f(v[2]), s0.z, h0.z), 0.f));
    o[3] = f2bf(fmaxf(fmaf(bf2f(v[3]), s0.w, h0.w), 0.f));
    o[4] = f2bf(fmaxf(fmaf(bf2f(v[4]), s1.x, h1.x), 0.f));
    o[5] = f2bf(fmaxf(fmaf(bf2f(v[5]), s1.y, h1.y), 0.f));
    o[6] = f2bf(fmaxf(fmaf(bf2f(v[6]), s1.z, h1.z), 0.f));
    o[7] = f2bf(fmaxf(fmaf(bf2f(v[7]), s1.w, h1.w), 0.f));
    *(ushort8v*)&H[i * 8] = o;
  }
}

// ---------------- final: BN+ReLU + transpose [b][n][o] bf16 -> out [b][o][n] f32 ----------------
__global__ __launch_bounds__(256) void bnreluT_kernel(const unsigned short* __restrict__ Y,
                                                      const float* __restrict__ scale,
                                                      const float* __restrict__ shift,
                                                      float* __restrict__ out) {
  __shared__ float t[64][65];
  int n0 = blockIdx.x * 64, o0 = blockIdx.y * 64, b = blockIdx.z;
  int tid = threadIdx.x, r = tid >> 2, q = tid & 3;
  const unsigned short* yp = Y + ((size_t)b * N + n0 + r) * 256 + o0 + q * 16;
#pragma unroll
  for (int h = 0; h < 2; ++h) {
    ushort8v v = *(const ushort8v*)(yp + h * 8);
#pragma unroll
    for (int i = 0; i < 8; ++i) {
      int oc = q * 16 + h * 8 + i;
      float f = fmaxf(fmaf(bf2f(v[i]), scale[o0 + oc], shift[o0 + oc]), 0.f);
      t[oc][r] = f;
    }
  }
  __syncthreads();
  float* op = out + ((size_t)b * 256 + o0 + r) * N + n0 + q * 16;
#pragma unroll
  for (int i = 0; i < 4; ++i) {
    float4 v = make_float4(t[r][q * 16 + i * 4 + 0], t[r][q * 16 + i * 4 + 1],
                           t[r][q * 16 + i * 4 + 2], t[r][q * 16 + i * 4 + 3]);
    *(float4*)(op + i * 4) = v;
  }
}

extern "C" void kernel_launch(void* const* d_in, const int* in_sizes, int n_in,
                              void* d_out, int out_size, void* d_ws, size_t ws_size,
                              hipStream_t stream) {
  const float* xyz1 = (const float*)d_in[0];
  const float* xyz2 = (const float*)d_in[1];
  const float* points1 = (const float*)d_in[2];
  const float* points2 = (const float*)d_in[3];
  const float* w0 = (const float*)d_in[4];
  const float* b0 = (const float*)d_in[5];
  const float* g0 = (const float*)d_in[6];
  const float* be0 = (const float*)d_in[7];
  const float* w1 = (const float*)d_in[8];
  const float* b1 = (const float*)d_in[9];
  const float* g1 = (const float*)d_in[10];
  const float* be1 = (const float*)d_in[11];
  float* out = (float*)d_out;

  char* ws = (char*)d_ws;
  int* idxbuf = (int*)ws;              ws += (size_t)CNT * 3 * 4;      // 768KB
  float* wbuf = (float*)ws;            ws += (size_t)CNT * 3 * 4;      // 768KB
  float* stats = (float*)ws;           ws += (size_t)8 * 256 * 4;      // 8KB
  float* sum0 = stats, *sumsq0 = stats + 256;
  float* sum1 = stats + 512, *sumsq1 = stats + 768;
  float* scale0 = stats + 1024, *shift0 = stats + 1280;
  float* scale1 = stats + 1536, *shift1 = stats + 1792;
  unsigned short* w0b = (unsigned short*)ws;  ws += (size_t)C * CIN * 2;   // 256KB
  unsigned short* w1b = (unsigned short*)ws;  ws += (size_t)C * C * 2;     // 128KB
  unsigned short* p2t = (unsigned short*)ws;  ws += (size_t)B * S * 256 * 2;   // 8MB
  unsigned short* Xb = (unsigned short*)ws;   ws += (size_t)B * N * 512 * 2;   // 64MB
  unsigned short* Yb = (unsigned short*)ws;   ws += (size_t)B * N * 256 * 2;   // 32MB
  unsigned short* Hb = Xb;  // reuse Xb after GEMM0 consumed it

  hipMemsetAsync(stats, 0, 4 * 256 * 4, stream);
  convw_kernel<<<dim3((C * CIN + C * C) / 256), 256, 0, stream>>>(w0, w1, w0b, w1b);
  tconv_kernel<<<dim3(N / 64, 4, B), 256, 0, stream>>>(points1, Xb, N, 512, 0);
  tconv_kernel<<<dim3(S / 64, 4, B), 256, 0, stream>>>(points2, p2t, S, 256, 0);
  nn3_kernel<<<dim3(B * N / 64), 256, 0, stream>>>(xyz1, xyz2, idxbuf, wbuf);
  gather_kernel<<<dim3(B * N / 64), 256, 0, stream>>>(p2t, idxbuf, wbuf, Xb);
  gemm_kernel<<<dim3(N / 128, 2, B), 256, 0, stream>>>(Xb, w0b, b0, Yb, CIN);
  stats_kernel<<<dim3(CNT / 256), 256, 0, stream>>>(Yb, sum0, sumsq0);
  bnparam_kernel<<<1, 256, 0, stream>>>(sum0, sumsq0, g0, be0, scale0, shift0);
  bnrelu_kernel<<<dim3(2048), 256, 0, stream>>>(Yb, scale0, shift0, Hb);
  gemm_kernel<<<dim3(N / 128, 2, B), 256, 0, stream>>>(Hb, w1b, b1, Yb, C);
  stats_kernel<<<dim3(CNT / 256), 256, 0, stream>>>(Yb, sum1, sumsq1);
  bnparam_kernel<<<1, 256, 0, stream>>>(sum1, sumsq1, g1, be1, scale1, shift1);
  bnreluT_kernel<<<dim3(N / 64, 4, B), 256, 0, stream>>>(Yb, scale1, shift1, out);
}